// Round 8
// baseline (514.458 us; speedup 1.0000x reference)
//
#include <hip/hip_runtime.h>
#include <hip/hip_bf16.h>

using bf16_t  = __hip_bfloat16;
using bf16x8  = __attribute__((ext_vector_type(8))) __bf16;
using f32x4   = __attribute__((ext_vector_type(4))) float;
using f32x16  = __attribute__((ext_vector_type(16))) float;
using u32x2   = __attribute__((ext_vector_type(2))) unsigned;

#define MFMA(a, b, c)   __builtin_amdgcn_mfma_f32_16x16x32_bf16((a), (b), (c), 0, 0, 0)
#define MFMA32(a, b, c) __builtin_amdgcn_mfma_f32_32x32x16_bf16((a), (b), (c), 0, 0, 0)

#define GLOAD_LDS(g, l) __builtin_amdgcn_global_load_lds(                      \
    (const __attribute__((address_space(1))) void*)(g),                        \
    (__attribute__((address_space(3))) void*)(l), 16, 0, 0)

static __device__ __forceinline__ unsigned pk_bf16(float lo, float hi) {
  unsigned r;
  asm volatile("v_cvt_pk_bf16_f32 %0, %1, %2" : "=v"(r) : "v"(lo), "v"(hi));
  return r;
}

static __device__ __forceinline__ void lane32_swap(unsigned& a, unsigned& b) {
#if __has_builtin(__builtin_amdgcn_permlane32_swap)
  u32x2 r = __builtin_amdgcn_permlane32_swap(a, b, false, false);
  a = r[0]; b = r[1];
#else
  asm volatile("v_permlane32_swap_b32 %0, %1" : "+v"(a), "+v"(b));
#endif
}

// B=8, C=256, N=4096(=64x64), 16 groups of 16 channels. f32 I/O, bf16 internal.

// -------- convert 4 weight matrices (256x256 f32) to bf16 ----------------
__global__ __launch_bounds__(256) void cvtw_kernel(
    const float* __restrict__ w0, const float* __restrict__ w1,
    const float* __restrict__ w2, const float* __restrict__ w3,
    bf16_t* __restrict__ dst)
{
  const float* s;
  switch (blockIdx.y) {
    case 0: s = w0; break;
    case 1: s = w1; break;
    case 2: s = w2; break;
    default: s = w3; break;
  }
  bf16_t* d = dst + (long)blockIdx.y * 65536;
  const int i = (blockIdx.x * 256 + threadIdx.x) * 4;
  float4 v = *(const float4*)(s + i);
  d[i + 0] = __float2bfloat16(v.x);
  d[i + 1] = __float2bfloat16(v.y);
  d[i + 2] = __float2bfloat16(v.z);
  d[i + 3] = __float2bfloat16(v.w);
}

// ---------------- GroupNorm (f32 in) -> transposed (N, C) bf16 -----------
__global__ __launch_bounds__(256) void gnorm_kernel(
    const float* __restrict__ xy,
    const float* __restrict__ nw,
    const float* __restrict__ nb,
    bf16_t* __restrict__ hn_t,
    bf16_t* __restrict__ yn_t)
{
  const int bx    = blockIdx.x;
  const int b     = bx >> 5;
  const int rest  = bx & 31;
  const int which = rest >> 4;
  const int g     = rest & 15;

  const float* src = xy + (((long)b * 512 + which * 256 + g * 16) << 12);
  bf16_t* dst = (which ? yn_t : hn_t) + ((long)b << 20) + g * 16;

  const int tid = threadIdx.x;

  float sum = 0.f, ss = 0.f;
  const float4* src4 = (const float4*)src;
  for (int i = tid; i < 16384; i += 256) {
    float4 v = src4[i];
    sum += (v.x + v.y) + (v.z + v.w);
    ss = fmaf(v.x, v.x, ss); ss = fmaf(v.y, v.y, ss);
    ss = fmaf(v.z, v.z, ss); ss = fmaf(v.w, v.w, ss);
  }
  #pragma unroll
  for (int off = 32; off > 0; off >>= 1) {
    sum += __shfl_down(sum, off);
    ss  += __shfl_down(ss, off);
  }
  __shared__ float rbuf[8];
  const int w = tid >> 6, lane = tid & 63;
  if (lane == 0) { rbuf[w] = sum; rbuf[4 + w] = ss; }
  __syncthreads();
  const float inv = 1.f / 65536.f;
  const float mu  = (rbuf[0] + rbuf[1] + rbuf[2] + rbuf[3]) * inv;
  const float var = (rbuf[4] + rbuf[5] + rbuf[6] + rbuf[7]) * inv - mu * mu;
  const float rs  = rsqrtf(var + 1e-6f);

  const int   cl = tid & 15;
  const float a  = nw[g * 16 + cl] * rs;
  const float c  = nb[g * 16 + cl] - mu * a;
  const float* srow = src + ((long)cl << 12);
  for (int n = tid >> 4; n < 4096; n += 16) {
    dst[((long)n << 8) + cl] = __float2bfloat16(fmaf(srow[n], a, c));
  }
}

// ---------------- NT GEMM: C[m][n] = sum_k A[m][k] * B[n][k]  (K = 256) ---
template <bool F32OUT>
__global__ __launch_bounds__(256) void gemm_nt_kernel(
    const bf16_t* __restrict__ A,  long sA,
    const bf16_t* __restrict__ Bm, long sB,
    void* __restrict__ Co_,        long sC,
    int Nn,
    const float* __restrict__ bias, int bias_row,
    const float* __restrict__ resid, long sR)
{
  const int b = blockIdx.z;
  A  += (long)b * sA;
  Bm += (long)b * sB;

  const int tid  = threadIdx.x;
  const int w    = tid >> 6, lane = tid & 63;
  const int rowq = lane & 15, kg = lane >> 4;
  const int m0   = blockIdx.x * 64 + w * 16;
  const int n0   = blockIdx.y * 64;

  f32x4 acc[4] = {};
  const bf16x8* arow = (const bf16x8*)(A + (long)(m0 + rowq) * 256 + kg * 8);
  #pragma unroll
  for (int kc = 0; kc < 8; ++kc) {
    bf16x8 af = arow[kc * 4];
    #pragma unroll
    for (int nt = 0; nt < 4; ++nt) {
      bf16x8 bfr = *(const bf16x8*)(Bm + (long)(n0 + nt * 16 + rowq) * 256 + kc * 32 + kg * 8);
      acc[nt] = MFMA(af, bfr, acc[nt]);
    }
  }
  const int r0 = kg * 4;
  #pragma unroll
  for (int nt = 0; nt < 4; ++nt) {
    #pragma unroll
    for (int r = 0; r < 4; ++r) {
      const int row = m0 + r0 + r;
      const int col = n0 + nt * 16 + rowq;
      float vv = acc[nt][r] + bias[bias_row ? row : col];
      if (resid) vv += resid[(long)b * sR + (long)row * Nn + col];
      const long ci = (long)b * sC + (long)row * Nn + col;
      if (F32OUT) ((float*)Co_)[ci] = vv;
      else        ((bf16_t*)Co_)[ci] = __float2bfloat16(vv);
    }
  }
}

// ---------------- Flash attention (kv-split partials) ----------------------
// grid (16 q-tiles, 8 batches, 2 kv-splits); 8 waves x 32 q-rows = 256 q/block.
// LDS 128KB: K,V double-buffered, KVBLK=64. 1 block/CU -> 2 waves/SIMD.
// Outputs UNNORMALIZED partial O^T (bf16) + per-q (m2, lsum) f32.
__global__ __launch_bounds__(512, 2) void attn_kernel(
    const bf16_t* __restrict__ Q,   // (B, N, C)
    const bf16_t* __restrict__ Kt,  // (B, N, C)
    const bf16_t* __restrict__ V,   // (B, C, N)
    bf16_t* __restrict__ P0,        // (B, N, C) partial split 0
    bf16_t* __restrict__ P1,        // (B, N, C) partial split 1
    float* __restrict__ ML)         // [split][b*4096+q] x {m, l}
{
  __shared__ bf16_t k_lds[2][64 * 256];   // 32KB/buf; row=kv, 32 chunks of 16B
  __shared__ bf16_t v_lds[2][256 * 64];   // 32KB/buf; row=c,  8 chunks of 16B

  const int b     = blockIdx.y;
  const int split = blockIdx.z;
  const long bo   = (long)b << 20;
  const bf16_t* q_t = Q  + bo;
  const bf16_t* k_t = Kt + bo + (long)split * 2048 * 256;
  const bf16_t* vb  = V  + bo + split * 2048;
  bf16_t*       po  = (split ? P1 : P0) + bo;

  const int tid = threadIdx.x;
  const int w   = tid >> 6, lane = tid & 63;
  const int ql  = lane & 31, hi = lane >> 5;
  const int q0  = blockIdx.x * 256 + w * 32;

  // staging offsets (global elems), swizzle-inverse pre-applied; LDS linear.
  int kgoff[4], vgoff[4];
  #pragma unroll
  for (int it = 0; it < 4; ++it) {
    const int cl = it * 512 + tid;          // 2048 chunks of 16B
    const int r  = cl >> 5, j = cl & 31;    // K: 64 rows x 32 chunks
    kgoff[it] = r * 256 + ((j ^ (r & 7)) << 3);
    const int c = cl >> 3, jv = cl & 7;     // V: 256 rows x 8 chunks
    vgoff[it] = c * 4096 + ((jv ^ (c & 7)) << 3);
  }

  // Q fragments (B-operand): lane holds Q[q0+ql][cs*16 + hi*8 .. +8]
  bf16x8 qf[16];
  #pragma unroll
  for (int cs = 0; cs < 16; ++cs)
    qf[cs] = *(const bf16x8*)(q_t + (long)(q0 + ql) * 256 + cs * 16 + hi * 8);

  f32x16 o[8] = {};            // O^T[c = cb*32 + (reg&3)+8*(reg>>2)+4*hi][q=ql]
  float m2 = -1e30f, lsum = 0.f;
  const float SC2 = 0.0625f * 1.44269504f;   // scale * log2(e)

  // prologue: stage tile 0 into buf 0
  #pragma unroll
  for (int it = 0; it < 4; ++it)
    GLOAD_LDS(k_t + kgoff[it], &k_lds[0][(it * 512 + tid) * 8]);
  #pragma unroll
  for (int it = 0; it < 4; ++it)
    GLOAD_LDS(vb + vgoff[it], &v_lds[0][(it * 512 + tid) * 8]);

  int cur = 0;
  for (int t = 0; t < 32; ++t) {
    const int kv0 = t << 6;
    __syncthreads();                        // buf[cur] staged; prior reads done
    if (t < 31) {
      #pragma unroll
      for (int it = 0; it < 4; ++it)
        GLOAD_LDS(k_t + (long)(kv0 + 64) * 256 + kgoff[it],
                  &k_lds[cur ^ 1][(it * 512 + tid) * 8]);
      #pragma unroll
      for (int it = 0; it < 4; ++it)
        GLOAD_LDS(vb + (kv0 + 64) + vgoff[it],
                  &v_lds[cur ^ 1][(it * 512 + tid) * 8]);
    }

    // S^T = K . Q^T : two 32x32 tiles (kv halves), K from LDS
    f32x16 s0 = {}, s1 = {};
    #pragma unroll
    for (int cs = 0; cs < 16; ++cs) {
      const int g = cs * 2 + hi;
      const int sw = (g ^ (ql & 7)) << 3;
      bf16x8 kf0 = *(const bf16x8*)(&k_lds[cur][ql * 256 + sw]);
      bf16x8 kf1 = *(const bf16x8*)(&k_lds[cur][(32 + ql) * 256 + sw]);
      s0 = MFMA32(kf0, qf[cs], s0);
      s1 = MFMA32(kf1, qf[cs], s1);
    }

    // online softmax (log2 domain); lane owns q=ql
    float p0[16], p1[16];
    #pragma unroll
    for (int i = 0; i < 16; ++i) { p0[i] = s0[i] * SC2; p1[i] = s1[i] * SC2; }
    float mx = p0[0];
    #pragma unroll
    for (int i = 1; i < 16; ++i) mx = fmaxf(mx, p0[i]);
    #pragma unroll
    for (int i = 0; i < 16; ++i) mx = fmaxf(mx, p1[i]);
    mx = fmaxf(mx, __shfl_xor(mx, 32));
    if (__any(mx > m2 + 11.5f)) {           // defer-max rescale
      const float mn = fmaxf(m2, mx);
      const float al = exp2f(m2 - mn);
      m2 = mn;
      lsum *= al;
      #pragma unroll
      for (int cb = 0; cb < 8; ++cb)
        #pragma unroll
        for (int i = 0; i < 16; ++i) o[cb][i] *= al;
    }
    float sm = 0.f;
    #pragma unroll
    for (int i = 0; i < 16; ++i) {
      p0[i] = exp2f(p0[i] - m2); sm += p0[i];
      p1[i] = exp2f(p1[i] - m2); sm += p1[i];
    }
    lsum += sm;                             // per-lane partial; merge at end

    // P^T B-operand assembly: cvt_pk pairs + permlane32_swap (no LDS)
    bf16x8 pb[4];
    {
      unsigned wd[8];
      #pragma unroll
      for (int j = 0; j < 8; ++j) wd[j] = pk_bf16(p0[2 * j], p0[2 * j + 1]);
      lane32_swap(wd[0], wd[2]); lane32_swap(wd[1], wd[3]);
      lane32_swap(wd[4], wd[6]); lane32_swap(wd[5], wd[7]);
      union { unsigned u[4]; bf16x8 v; } a0, a1;
      a0.u[0] = wd[0]; a0.u[1] = wd[1]; a0.u[2] = wd[2]; a0.u[3] = wd[3];
      a1.u[0] = wd[4]; a1.u[1] = wd[5]; a1.u[2] = wd[6]; a1.u[3] = wd[7];
      pb[0] = a0.v; pb[1] = a1.v;
      #pragma unroll
      for (int j = 0; j < 8; ++j) wd[j] = pk_bf16(p1[2 * j], p1[2 * j + 1]);
      lane32_swap(wd[0], wd[2]); lane32_swap(wd[1], wd[3]);
      lane32_swap(wd[4], wd[6]); lane32_swap(wd[5], wd[7]);
      a0.u[0] = wd[0]; a0.u[1] = wd[1]; a0.u[2] = wd[2]; a0.u[3] = wd[3];
      a1.u[0] = wd[4]; a1.u[1] = wd[5]; a1.u[2] = wd[6]; a1.u[3] = wd[7];
      pb[2] = a0.v; pb[3] = a1.v;
    }

    // O^T += V . P^T, V from LDS
    #pragma unroll
    for (int ks = 0; ks < 4; ++ks) {
      const int g = ks * 2 + hi;
      #pragma unroll
      for (int cb = 0; cb < 8; ++cb) {
        const int c = cb * 32 + ql;
        bf16x8 vf = *(const bf16x8*)(&v_lds[cur][c * 64 + ((g ^ (c & 7)) << 3)]);
        o[cb] = MFMA32(vf, pb[ks], o[cb]);
      }
    }
    cur ^= 1;
  }

  // epilogue: merge l across lane pair; store UNNORMALIZED O^T + (m, l)
  lsum += __shfl_xor(lsum, 32);
  if (hi == 0) {
    float2 ml = make_float2(m2, lsum);
    *(float2*)(ML + ((long)split * 32768 + b * 4096 + q0 + ql) * 2) = ml;
  }
  bf16_t* hrow = po + (long)(q0 + ql) * 256;
  #pragma unroll
  for (int cb = 0; cb < 8; ++cb) {
    #pragma unroll
    for (int pg = 0; pg < 4; ++pg) {
      unsigned u0 = pk_bf16(o[cb][pg * 4 + 0], o[cb][pg * 4 + 1]);
      unsigned u1 = pk_bf16(o[cb][pg * 4 + 2], o[cb][pg * 4 + 3]);
      uint2 uu = make_uint2(u0, u1);
      *(uint2*)(hrow + cb * 32 + pg * 8 + hi * 4) = uu;
    }
  }
}

// ---------------- merge 2 kv-split partials -> h_t (B,N,C) bf16 -----------
__global__ __launch_bounds__(256) void attn_merge_kernel(
    const bf16_t* __restrict__ P0, const bf16_t* __restrict__ P1,
    const float* __restrict__ ML, bf16_t* __restrict__ Ht)
{
  const long e = ((long)blockIdx.x * 256 + threadIdx.x) * 8;   // 8 elems/thread
  const long r = e >> 8;                                       // flat q-row
  const float2 ml0 = *(const float2*)(ML + r * 2);
  const float2 ml1 = *(const float2*)(ML + (32768 + r) * 2);
  const float mm = fmaxf(ml0.x, ml1.x);
  const float w0 = exp2f(ml0.x - mm), w1 = exp2f(ml1.x - mm);
  const float il = 1.f / (ml0.y * w0 + ml1.y * w1);
  const float a0 = w0 * il, a1 = w1 * il;

  uint4 u0 = *(const uint4*)(P0 + e);
  uint4 u1 = *(const uint4*)(P1 + e);
  unsigned out[4];
  const unsigned* q0 = (const unsigned*)&u0;
  const unsigned* q1 = (const unsigned*)&u1;
  #pragma unroll
  for (int j = 0; j < 4; ++j) {
    float lo0 = __uint_as_float(q0[j] << 16);
    float hi0 = __uint_as_float(q0[j] & 0xffff0000u);
    float lo1 = __uint_as_float(q1[j] << 16);
    float hi1 = __uint_as_float(q1[j] & 0xffff0000u);
    out[j] = pk_bf16(fmaf(lo0, a0, lo1 * a1), fmaf(hi0, a0, hi1 * a1));
  }
  *(uint4*)(Ht + e) = *(uint4*)out;
}

extern "C" void kernel_launch(void* const* d_in, const int* in_sizes, int n_in,
                              void* d_out, int out_size, void* d_ws, size_t ws_size,
                              hipStream_t stream)
{
  const float* xy  = (const float*)d_in[0];
  const float* nw  = (const float*)d_in[1];
  const float* nb  = (const float*)d_in[2];
  const float* q_w = (const float*)d_in[3];
  const float* q_b = (const float*)d_in[4];
  const float* k_w = (const float*)d_in[5];
  const float* k_b = (const float*)d_in[6];
  const float* v_w = (const float*)d_in[7];
  const float* v_b = (const float*)d_in[8];
  const float* p_w = (const float*)d_in[9];
  const float* p_b = (const float*)d_in[10];
  float*  out = (float*)d_out;
  bf16_t* ws  = (bf16_t*)d_ws;

  const long SZ = (long)8 * 4096 * 256;
  bf16_t* wq   = ws;
  bf16_t* wk   = ws + 65536;
  bf16_t* wv   = ws + 131072;
  bf16_t* wp   = ws + 196608;
  bf16_t* hn_t = ws + 262144;
  bf16_t* yn_t = hn_t + SZ;
  bf16_t* q_t  = hn_t + 2 * SZ;
  bf16_t* k_t  = hn_t + 3 * SZ;
  bf16_t* vbuf = hn_t + 4 * SZ;
  float*  mlb  = (float*)(hn_t + 5 * SZ);   // 2 x 32768 x float2 = 512KB
  bf16_t* part0 = hn_t;                     // dead after v GEMM
  bf16_t* part1 = yn_t;                     // dead after q GEMM
  bf16_t* h_t   = q_t;                      // dead after attn

  const long nc = (long)4096 * 256;

  cvtw_kernel<<<dim3(64, 4), 256, 0, stream>>>(q_w, k_w, v_w, p_w, wq);

  gnorm_kernel<<<256, 256, 0, stream>>>(xy, nw, nb, hn_t, yn_t);

  gemm_nt_kernel<false><<<dim3(64, 4, 8), 256, 0, stream>>>(
      yn_t, nc, wq, 0, q_t, nc, 256, q_b, 0, nullptr, 0);
  gemm_nt_kernel<false><<<dim3(64, 4, 8), 256, 0, stream>>>(
      hn_t, nc, wk, 0, k_t, nc, 256, k_b, 0, nullptr, 0);
  gemm_nt_kernel<false><<<dim3(4, 64, 8), 256, 0, stream>>>(
      wv, 0, hn_t, nc, vbuf, nc, 4096, v_b, 1, nullptr, 0);

  attn_kernel<<<dim3(16, 8, 2), 512, 0, stream>>>(q_t, k_t, vbuf,
                                                  part0, part1, mlb);

  attn_merge_kernel<<<4096, 256, 0, stream>>>(part0, part1, mlb, h_t);

  gemm_nt_kernel<true><<<dim3(4, 64, 8), 256, 0, stream>>>(
      wp, 0, h_t, nc, out, nc, 4096, p_b, 1, xy, (long)512 * 4096);
}

// Round 9
// 433.427 us; speedup vs baseline: 1.1870x; 1.1870x over previous
//
#include <hip/hip_runtime.h>
#include <hip/hip_bf16.h>

using bf16_t  = __hip_bfloat16;
using bf16x8  = __attribute__((ext_vector_type(8))) __bf16;
using f32x4   = __attribute__((ext_vector_type(4))) float;
using f32x16  = __attribute__((ext_vector_type(16))) float;
using u32x2   = __attribute__((ext_vector_type(2))) unsigned;

#define MFMA(a, b, c)   __builtin_amdgcn_mfma_f32_16x16x32_bf16((a), (b), (c), 0, 0, 0)
#define MFMA32(a, b, c) __builtin_amdgcn_mfma_f32_32x32x16_bf16((a), (b), (c), 0, 0, 0)

#define GLOAD_LDS(g, l) __builtin_amdgcn_global_load_lds(                      \
    (const __attribute__((address_space(1))) void*)(g),                        \
    (__attribute__((address_space(3))) void*)(l), 16, 0, 0)

static __device__ __forceinline__ unsigned pk_bf16(float lo, float hi) {
  unsigned r;
  asm volatile("v_cvt_pk_bf16_f32 %0, %1, %2" : "=v"(r) : "v"(lo), "v"(hi));
  return r;
}

static __device__ __forceinline__ void lane32_swap(unsigned& a, unsigned& b) {
#if __has_builtin(__builtin_amdgcn_permlane32_swap)
  u32x2 r = __builtin_amdgcn_permlane32_swap(a, b, false, false);
  a = r[0]; b = r[1];
#else
  asm volatile("v_permlane32_swap_b32 %0, %1" : "+v"(a), "+v"(b));
#endif
}

// B=8, C=256, N=4096(=64x64), 16 groups of 16 channels. f32 I/O, bf16 internal.

// -------- convert 4 weight matrices (256x256 f32) to bf16 ----------------
__global__ __launch_bounds__(256) void cvtw_kernel(
    const float* __restrict__ w0, const float* __restrict__ w1,
    const float* __restrict__ w2, const float* __restrict__ w3,
    bf16_t* __restrict__ dst)
{
  const float* s;
  switch (blockIdx.y) {
    case 0: s = w0; break;
    case 1: s = w1; break;
    case 2: s = w2; break;
    default: s = w3; break;
  }
  bf16_t* d = dst + (long)blockIdx.y * 65536;
  const int i = (blockIdx.x * 256 + threadIdx.x) * 4;
  float4 v = *(const float4*)(s + i);
  d[i + 0] = __float2bfloat16(v.x);
  d[i + 1] = __float2bfloat16(v.y);
  d[i + 2] = __float2bfloat16(v.z);
  d[i + 3] = __float2bfloat16(v.w);
}

// ---------------- GroupNorm (f32 in) -> transposed (N, C) bf16 -----------
__global__ __launch_bounds__(256) void gnorm_kernel(
    const float* __restrict__ xy,
    const float* __restrict__ nw,
    const float* __restrict__ nb,
    bf16_t* __restrict__ hn_t,
    bf16_t* __restrict__ yn_t)
{
  const int bx    = blockIdx.x;
  const int b     = bx >> 5;
  const int rest  = bx & 31;
  const int which = rest >> 4;
  const int g     = rest & 15;

  const float* src = xy + (((long)b * 512 + which * 256 + g * 16) << 12);
  bf16_t* dst = (which ? yn_t : hn_t) + ((long)b << 20) + g * 16;

  const int tid = threadIdx.x;

  float sum = 0.f, ss = 0.f;
  const float4* src4 = (const float4*)src;
  for (int i = tid; i < 16384; i += 256) {
    float4 v = src4[i];
    sum += (v.x + v.y) + (v.z + v.w);
    ss = fmaf(v.x, v.x, ss); ss = fmaf(v.y, v.y, ss);
    ss = fmaf(v.z, v.z, ss); ss = fmaf(v.w, v.w, ss);
  }
  #pragma unroll
  for (int off = 32; off > 0; off >>= 1) {
    sum += __shfl_down(sum, off);
    ss  += __shfl_down(ss, off);
  }
  __shared__ float rbuf[8];
  const int w = tid >> 6, lane = tid & 63;
  if (lane == 0) { rbuf[w] = sum; rbuf[4 + w] = ss; }
  __syncthreads();
  const float inv = 1.f / 65536.f;
  const float mu  = (rbuf[0] + rbuf[1] + rbuf[2] + rbuf[3]) * inv;
  const float var = (rbuf[4] + rbuf[5] + rbuf[6] + rbuf[7]) * inv - mu * mu;
  const float rs  = rsqrtf(var + 1e-6f);

  const int   cl = tid & 15;
  const float a  = nw[g * 16 + cl] * rs;
  const float c  = nb[g * 16 + cl] - mu * a;
  const float* srow = src + ((long)cl << 12);
  for (int n = tid >> 4; n < 4096; n += 16) {
    dst[((long)n << 8) + cl] = __float2bfloat16(fmaf(srow[n], a, c));
  }
}

// ---------------- NT GEMM: C[m][n] = sum_k A[m][k] * B[n][k]  (K = 256) ---
template <bool F32OUT>
__global__ __launch_bounds__(256) void gemm_nt_kernel(
    const bf16_t* __restrict__ A,  long sA,
    const bf16_t* __restrict__ Bm, long sB,
    void* __restrict__ Co_,        long sC,
    int Nn,
    const float* __restrict__ bias, int bias_row,
    const float* __restrict__ resid, long sR)
{
  const int b = blockIdx.z;
  A  += (long)b * sA;
  Bm += (long)b * sB;

  const int tid  = threadIdx.x;
  const int w    = tid >> 6, lane = tid & 63;
  const int rowq = lane & 15, kg = lane >> 4;
  const int m0   = blockIdx.x * 64 + w * 16;
  const int n0   = blockIdx.y * 64;

  f32x4 acc[4] = {};
  const bf16x8* arow = (const bf16x8*)(A + (long)(m0 + rowq) * 256 + kg * 8);
  #pragma unroll
  for (int kc = 0; kc < 8; ++kc) {
    bf16x8 af = arow[kc * 4];
    #pragma unroll
    for (int nt = 0; nt < 4; ++nt) {
      bf16x8 bfr = *(const bf16x8*)(Bm + (long)(n0 + nt * 16 + rowq) * 256 + kc * 32 + kg * 8);
      acc[nt] = MFMA(af, bfr, acc[nt]);
    }
  }
  const int r0 = kg * 4;
  #pragma unroll
  for (int nt = 0; nt < 4; ++nt) {
    #pragma unroll
    for (int r = 0; r < 4; ++r) {
      const int row = m0 + r0 + r;
      const int col = n0 + nt * 16 + rowq;
      float vv = acc[nt][r] + bias[bias_row ? row : col];
      if (resid) vv += resid[(long)b * sR + (long)row * Nn + col];
      const long ci = (long)b * sC + (long)row * Nn + col;
      if (F32OUT) ((float*)Co_)[ci] = vv;
      else        ((bf16_t*)Co_)[ci] = __float2bfloat16(vv);
    }
  }
}

// ---------------- Flash attention (kv-split partials) ----------------------
// grid (32 q-tiles, 8 batches, 2 kv-splits) = 512 blocks; 256 thr = 4 waves
// x 32 q-rows. KVBLK=32; LDS 64KB (K 2x16K XOR-swizzled + V 2x16K chunk-major)
// -> 2 INDEPENDENT blocks/CU -> 2 waves/SIMD from different barrier groups.
__global__ __launch_bounds__(256, 2) void attn_kernel(
    const bf16_t* __restrict__ Q,   // (B, N, C)
    const bf16_t* __restrict__ Kt,  // (B, N, C)
    const bf16_t* __restrict__ V,   // (B, C, N)
    bf16_t* __restrict__ P0,        // (B, N, C) partial split 0
    bf16_t* __restrict__ P1,        // (B, N, C) partial split 1
    float* __restrict__ ML)         // [split][b*4096+q] x {m, l}
{
  __shared__ bf16_t k_lds[2][32 * 256];   // 16KB/buf; row=kv, 32 chunks of 16B
  __shared__ bf16_t v_lds[2][4 * 256 * 8];// 16KB/buf; chunk-major [g][c][8]

  const int b     = blockIdx.y;
  const int split = blockIdx.z;
  const long bo   = (long)b << 20;
  const bf16_t* q_t = Q  + bo;
  const bf16_t* k_t = Kt + bo + (long)split * 2048 * 256;
  const bf16_t* vb  = V  + bo + split * 2048;
  bf16_t*       po  = (split ? P1 : P0) + bo;

  const int tid = threadIdx.x;
  const int w   = tid >> 6, lane = tid & 63;
  const int ql  = lane & 31, hi = lane >> 5;
  const int q0  = blockIdx.x * 128 + w * 32;

  // staging source offsets (global elems). K: swizzle-inverse pre-applied.
  // V: chunk cl -> (c = cl&255, g = cl>>8), src = c*4096 + g*8 (+kv0).
  int kgoff[4], vgoff[4];
  #pragma unroll
  for (int it = 0; it < 4; ++it) {
    const int cl = it * 256 + tid;          // 1024 chunks of 16B each
    const int r  = cl >> 5, j = cl & 31;    // K: 32 rows x 32 chunks
    kgoff[it] = r * 256 + ((j ^ (r & 7)) << 3);
    const int c = cl & 255, g = cl >> 8;    // V: 4 kv-chunks x 256 rows
    vgoff[it] = c * 4096 + g * 8;
  }

  // Q fragments (B-operand): lane holds Q[q0+ql][cs*16 + hi*8 .. +8]
  bf16x8 qf[16];
  #pragma unroll
  for (int cs = 0; cs < 16; ++cs)
    qf[cs] = *(const bf16x8*)(q_t + (long)(q0 + ql) * 256 + cs * 16 + hi * 8);

  f32x16 o[8] = {};            // O^T[c = cb*32 + (reg&3)+8*(reg>>2)+4*hi][q=ql]
  float m2 = -1e30f, lsum = 0.f;
  const float SC2 = 0.0625f * 1.44269504f;   // scale * log2(e)

  // prologue: stage tile 0 into buf 0
  #pragma unroll
  for (int it = 0; it < 4; ++it)
    GLOAD_LDS(k_t + kgoff[it], &k_lds[0][(it * 256 + tid) * 8]);
  #pragma unroll
  for (int it = 0; it < 4; ++it)
    GLOAD_LDS(vb + vgoff[it], &v_lds[0][(it * 256 + tid) * 8]);

  int cur = 0;
  for (int t = 0; t < 64; ++t) {
    const int kv0 = t << 5;
    __syncthreads();                        // buf[cur] staged; prior reads done
    if (t < 63) {
      #pragma unroll
      for (int it = 0; it < 4; ++it)
        GLOAD_LDS(k_t + (long)(kv0 + 32) * 256 + kgoff[it],
                  &k_lds[cur ^ 1][(it * 256 + tid) * 8]);
      #pragma unroll
      for (int it = 0; it < 4; ++it)
        GLOAD_LDS(vb + (kv0 + 32) + vgoff[it],
                  &v_lds[cur ^ 1][(it * 256 + tid) * 8]);
    }

    // S^T = K . Q^T : one 32x32 tile, K from LDS (XOR-swizzled rows)
    f32x16 s0 = {};
    #pragma unroll
    for (int cs = 0; cs < 16; ++cs) {
      const int ch = cs * 2 + hi;
      bf16x8 kf = *(const bf16x8*)(
          &k_lds[cur][ql * 256 + ((ch ^ (ql & 7)) << 3)]);
      s0 = MFMA32(kf, qf[cs], s0);
    }

    // online softmax (log2 domain); lane owns q=ql, 16 kv rows lane-local
    float p0[16];
    #pragma unroll
    for (int i = 0; i < 16; ++i) p0[i] = s0[i] * SC2;
    float mx = p0[0];
    #pragma unroll
    for (int i = 1; i < 16; ++i) mx = fmaxf(mx, p0[i]);
    mx = fmaxf(mx, __shfl_xor(mx, 32));
    if (__any(mx > m2 + 11.5f)) {           // defer-max rescale
      const float mn = fmaxf(m2, mx);
      const float al = exp2f(m2 - mn);
      m2 = mn;
      lsum *= al;
      #pragma unroll
      for (int cb = 0; cb < 8; ++cb)
        #pragma unroll
        for (int i = 0; i < 16; ++i) o[cb][i] *= al;
    }
    float sm = 0.f;
    #pragma unroll
    for (int i = 0; i < 16; ++i) {
      p0[i] = exp2f(p0[i] - m2); sm += p0[i];
    }
    sm += __shfl_xor(sm, 32);
    lsum += sm;

    // P^T B-operand assembly: cvt_pk pairs + permlane32_swap (no LDS)
    bf16x8 pb[2];
    {
      unsigned wd[8];
      #pragma unroll
      for (int j = 0; j < 8; ++j) wd[j] = pk_bf16(p0[2 * j], p0[2 * j + 1]);
      lane32_swap(wd[0], wd[2]); lane32_swap(wd[1], wd[3]);
      lane32_swap(wd[4], wd[6]); lane32_swap(wd[5], wd[7]);
      union { unsigned u[4]; bf16x8 v; } a0, a1;
      a0.u[0] = wd[0]; a0.u[1] = wd[1]; a0.u[2] = wd[2]; a0.u[3] = wd[3];
      a1.u[0] = wd[4]; a1.u[1] = wd[5]; a1.u[2] = wd[6]; a1.u[3] = wd[7];
      pb[0] = a0.v; pb[1] = a1.v;
    }

    // O^T += V . P^T, V from LDS chunk-major [g][c]
    #pragma unroll
    for (int ks = 0; ks < 2; ++ks) {
      const int g = ks * 2 + hi;
      #pragma unroll
      for (int cb = 0; cb < 8; ++cb) {
        const int c = cb * 32 + ql;
        bf16x8 vf = *(const bf16x8*)(&v_lds[cur][(g * 256 + c) * 8]);
        o[cb] = MFMA32(vf, pb[ks], o[cb]);
      }
    }
    cur ^= 1;
  }

  // epilogue: merge l across lane pair; store UNNORMALIZED O^T + (m, l)
  if (hi == 0) {
    float2 ml = make_float2(m2, lsum);
    *(float2*)(ML + ((long)split * 32768 + b * 4096 + q0 + ql) * 2) = ml;
  }
  bf16_t* hrow = po + (long)(q0 + ql) * 256;
  #pragma unroll
  for (int cb = 0; cb < 8; ++cb) {
    #pragma unroll
    for (int pg = 0; pg < 4; ++pg) {
      unsigned u0 = pk_bf16(o[cb][pg * 4 + 0], o[cb][pg * 4 + 1]);
      unsigned u1 = pk_bf16(o[cb][pg * 4 + 2], o[cb][pg * 4 + 3]);
      uint2 uu = make_uint2(u0, u1);
      *(uint2*)(hrow + cb * 32 + pg * 8 + hi * 4) = uu;
    }
  }
}

// ---------------- merge 2 kv-split partials -> h_t (B,N,C) bf16 -----------
__global__ __launch_bounds__(256) void attn_merge_kernel(
    const bf16_t* __restrict__ P0, const bf16_t* __restrict__ P1,
    const float* __restrict__ ML, bf16_t* __restrict__ Ht)
{
  const long e = ((long)blockIdx.x * 256 + threadIdx.x) * 8;   // 8 elems/thread
  const long r = e >> 8;                                       // flat q-row
  const float2 ml0 = *(const float2*)(ML + r * 2);
  const float2 ml1 = *(const float2*)(ML + (32768 + r) * 2);
  const float mm = fmaxf(ml0.x, ml1.x);
  const float w0 = exp2f(ml0.x - mm), w1 = exp2f(ml1.x - mm);
  const float il = 1.f / (ml0.y * w0 + ml1.y * w1);
  const float a0 = w0 * il, a1 = w1 * il;

  uint4 u0 = *(const uint4*)(P0 + e);
  uint4 u1 = *(const uint4*)(P1 + e);
  unsigned out[4];
  const unsigned* q0 = (const unsigned*)&u0;
  const unsigned* q1 = (const unsigned*)&u1;
  #pragma unroll
  for (int j = 0; j < 4; ++j) {
    float lo0 = __uint_as_float(q0[j] << 16);
    float hi0 = __uint_as_float(q0[j] & 0xffff0000u);
    float lo1 = __uint_as_float(q1[j] << 16);
    float hi1 = __uint_as_float(q1[j] & 0xffff0000u);
    out[j] = pk_bf16(fmaf(lo0, a0, lo1 * a1), fmaf(hi0, a0, hi1 * a1));
  }
  *(uint4*)(Ht + e) = *(uint4*)out;
}

extern "C" void kernel_launch(void* const* d_in, const int* in_sizes, int n_in,
                              void* d_out, int out_size, void* d_ws, size_t ws_size,
                              hipStream_t stream)
{
  const float* xy  = (const float*)d_in[0];
  const float* nw  = (const float*)d_in[1];
  const float* nb  = (const float*)d_in[2];
  const float* q_w = (const float*)d_in[3];
  const float* q_b = (const float*)d_in[4];
  const float* k_w = (const float*)d_in[5];
  const float* k_b = (const float*)d_in[6];
  const float* v_w = (const float*)d_in[7];
  const float* v_b = (const float*)d_in[8];
  const float* p_w = (const float*)d_in[9];
  const float* p_b = (const float*)d_in[10];
  float*  out = (float*)d_out;
  bf16_t* ws  = (bf16_t*)d_ws;

  const long SZ = (long)8 * 4096 * 256;
  bf16_t* wq   = ws;
  bf16_t* wk   = ws + 65536;
  bf16_t* wv   = ws + 131072;
  bf16_t* wp   = ws + 196608;
  bf16_t* hn_t = ws + 262144;
  bf16_t* yn_t = hn_t + SZ;
  bf16_t* q_t  = hn_t + 2 * SZ;
  bf16_t* k_t  = hn_t + 3 * SZ;
  bf16_t* vbuf = hn_t + 4 * SZ;
  float*  mlb  = (float*)(hn_t + 5 * SZ);   // 2 x 32768 x float2 = 512KB
  bf16_t* part0 = hn_t;                     // dead after v GEMM
  bf16_t* part1 = yn_t;                     // dead after q GEMM
  bf16_t* h_t   = q_t;                      // dead after attn

  const long nc = (long)4096 * 256;

  cvtw_kernel<<<dim3(64, 4), 256, 0, stream>>>(q_w, k_w, v_w, p_w, wq);

  gnorm_kernel<<<256, 256, 0, stream>>>(xy, nw, nb, hn_t, yn_t);

  gemm_nt_kernel<false><<<dim3(64, 4, 8), 256, 0, stream>>>(
      yn_t, nc, wq, 0, q_t, nc, 256, q_b, 0, nullptr, 0);
  gemm_nt_kernel<false><<<dim3(64, 4, 8), 256, 0, stream>>>(
      hn_t, nc, wk, 0, k_t, nc, 256, k_b, 0, nullptr, 0);
  gemm_nt_kernel<false><<<dim3(4, 64, 8), 256, 0, stream>>>(
      wv, 0, hn_t, nc, vbuf, nc, 4096, v_b, 1, nullptr, 0);

  attn_kernel<<<dim3(32, 8, 2), 256, 0, stream>>>(q_t, k_t, vbuf,
                                                  part0, part1, mlb);

  attn_merge_kernel<<<4096, 256, 0, stream>>>(part0, part1, mlb, h_t);

  gemm_nt_kernel<true><<<dim3(4, 64, 8), 256, 0, stream>>>(
      wp, 0, h_t, nc, out, nc, 4096, p_b, 1, xy, (long)512 * 4096);
}

// Round 10
// 364.910 us; speedup vs baseline: 1.4098x; 1.1878x over previous
//
#include <hip/hip_runtime.h>
#include <hip/hip_bf16.h>

using bf16_t  = __hip_bfloat16;
using bf16x8  = __attribute__((ext_vector_type(8))) __bf16;
using f32x4   = __attribute__((ext_vector_type(4))) float;
using f32x16  = __attribute__((ext_vector_type(16))) float;
using u32x2   = __attribute__((ext_vector_type(2))) unsigned;

#define MFMA32(a, b, c) __builtin_amdgcn_mfma_f32_32x32x16_bf16((a), (b), (c), 0, 0, 0)

#define GLOAD_LDS(g, l) __builtin_amdgcn_global_load_lds(                      \
    (const __attribute__((address_space(1))) void*)(g),                        \
    (__attribute__((address_space(3))) void*)(l), 16, 0, 0)

static __device__ __forceinline__ unsigned pk_bf16(float lo, float hi) {
  unsigned r;
  asm volatile("v_cvt_pk_bf16_f32 %0, %1, %2" : "=v"(r) : "v"(lo), "v"(hi));
  return r;
}

static __device__ __forceinline__ void lane32_swap(unsigned& a, unsigned& b) {
#if __has_builtin(__builtin_amdgcn_permlane32_swap)
  u32x2 r = __builtin_amdgcn_permlane32_swap(a, b, false, false);
  a = r[0]; b = r[1];
#else
  asm volatile("v_permlane32_swap_b32 %0, %1" : "+v"(a), "+v"(b));
#endif
}

// B=8, C=256, N=4096(=64x64), 16 groups of 16 channels. f32 I/O, bf16 internal.

// -------- convert 4 weight matrices (256x256 f32) to bf16 ----------------
__global__ __launch_bounds__(256) void cvtw_kernel(
    const float* __restrict__ w0, const float* __restrict__ w1,
    const float* __restrict__ w2, const float* __restrict__ w3,
    bf16_t* __restrict__ dst)
{
  const float* s;
  switch (blockIdx.y) {
    case 0: s = w0; break;
    case 1: s = w1; break;
    case 2: s = w2; break;
    default: s = w3; break;
  }
  bf16_t* d = dst + (long)blockIdx.y * 65536;
  const int i = (blockIdx.x * 256 + threadIdx.x) * 4;
  float4 v = *(const float4*)(s + i);
  d[i + 0] = __float2bfloat16(v.x);
  d[i + 1] = __float2bfloat16(v.y);
  d[i + 2] = __float2bfloat16(v.z);
  d[i + 3] = __float2bfloat16(v.w);
}

// ---------------- GroupNorm (f32 in) -> transposed (N, C) bf16 -----------
__global__ __launch_bounds__(256) void gnorm_kernel(
    const float* __restrict__ xy,
    const float* __restrict__ nw,
    const float* __restrict__ nb,
    bf16_t* __restrict__ hn_t,
    bf16_t* __restrict__ yn_t)
{
  const int bx    = blockIdx.x;
  const int b     = bx >> 5;
  const int rest  = bx & 31;
  const int which = rest >> 4;
  const int g     = rest & 15;

  const float* src = xy + (((long)b * 512 + which * 256 + g * 16) << 12);
  bf16_t* dst = (which ? yn_t : hn_t) + ((long)b << 20) + g * 16;

  const int tid = threadIdx.x;

  float sum = 0.f, ss = 0.f;
  const float4* src4 = (const float4*)src;
  for (int i = tid; i < 16384; i += 256) {
    float4 v = src4[i];
    sum += (v.x + v.y) + (v.z + v.w);
    ss = fmaf(v.x, v.x, ss); ss = fmaf(v.y, v.y, ss);
    ss = fmaf(v.z, v.z, ss); ss = fmaf(v.w, v.w, ss);
  }
  #pragma unroll
  for (int off = 32; off > 0; off >>= 1) {
    sum += __shfl_down(sum, off);
    ss  += __shfl_down(ss, off);
  }
  __shared__ float rbuf[8];
  const int w = tid >> 6, lane = tid & 63;
  if (lane == 0) { rbuf[w] = sum; rbuf[4 + w] = ss; }
  __syncthreads();
  const float inv = 1.f / 65536.f;
  const float mu  = (rbuf[0] + rbuf[1] + rbuf[2] + rbuf[3]) * inv;
  const float var = (rbuf[4] + rbuf[5] + rbuf[6] + rbuf[7]) * inv - mu * mu;
  const float rs  = rsqrtf(var + 1e-6f);

  const int   cl = tid & 15;
  const float a  = nw[g * 16 + cl] * rs;
  const float c  = nb[g * 16 + cl] - mu * a;
  const float* srow = src + ((long)cl << 12);
  for (int n = tid >> 4; n < 4096; n += 16) {
    dst[((long)n << 8) + cl] = __float2bfloat16(fmaf(srow[n], a, c));
  }
}

// -------- staged NT GEMM: D[m][n] = sum_k A[m,k] B[n,k]  (K = 256) --------
// 64x64 tile; A-tile and B-tile (64x256 bf16 = 32KB each) staged via
// global_load_lds with row-XOR swizzle; one barrier; 4 waves x (32x32 out,
// MFMA32). LDS 64KB -> 2 blocks/CU; deep block queue hides staging latency.
template <bool F32OUT>
__global__ __launch_bounds__(256, 2) void gemm_st_kernel(
    const bf16_t* __restrict__ A,  long sA,
    const bf16_t* __restrict__ Bm, long sB,
    void* __restrict__ Co_,        long sC,
    int Nn,
    const float* __restrict__ bias, int bias_row,
    const float* __restrict__ resid, long sR)
{
  __shared__ bf16_t a_lds[64 * 256];
  __shared__ bf16_t b_lds[64 * 256];

  const int b   = blockIdx.z;
  const int m0  = blockIdx.x * 64;
  const int n0  = blockIdx.y * 64;
  const int tid = threadIdx.x;
  const int w   = tid >> 6, lane = tid & 63;
  const int ql  = lane & 31, hi = lane >> 5;

  const bf16_t* Ag = A  + (long)b * sA + (long)m0 * 256;
  const bf16_t* Bg = Bm + (long)b * sB + (long)n0 * 256;

  // stage both tiles (swizzle-inverse on global source; LDS dest linear)
  #pragma unroll
  for (int it = 0; it < 8; ++it) {
    const int cl  = it * 256 + tid;          // 2048 chunks of 16B
    const int r   = cl >> 5, j = cl & 31;    // 64 rows x 32 chunks
    const int off = r * 256 + ((j ^ (r & 7)) << 3);
    GLOAD_LDS(Ag + off, &a_lds[cl * 8]);
    GLOAD_LDS(Bg + off, &b_lds[cl * 8]);
  }
  __syncthreads();

  const int mb = (w & 1) * 32, nb = (w >> 1) * 32;
  const int sw = ql & 7;

  f32x16 acc = {};
  #pragma unroll
  for (int t = 0; t < 16; ++t) {
    const int ch = t * 2 + hi;
    bf16x8 af = *(const bf16x8*)(&a_lds[(mb + ql) * 256 + ((ch ^ sw) << 3)]);
    bf16x8 bf = *(const bf16x8*)(&b_lds[(nb + ql) * 256 + ((ch ^ sw) << 3)]);
    acc = MFMA32(af, bf, acc);               // D rows = A rows, cols = B rows
  }

  // D layout: col = ql, row = (r&3) + 8*(r>>2) + 4*hi
  #pragma unroll
  for (int r = 0; r < 16; ++r) {
    const int grow = m0 + mb + (r & 3) + 8 * (r >> 2) + 4 * hi;
    const int gcol = n0 + nb + ql;
    float vv = acc[r] + bias[bias_row ? grow : gcol];
    if (resid) vv += resid[(long)b * sR + (long)grow * Nn + gcol];
    const long ci = (long)b * sC + (long)grow * Nn + gcol;
    if (F32OUT) ((float*)Co_)[ci] = vv;
    else        ((bf16_t*)Co_)[ci] = __float2bfloat16(vv);
  }
}

// ---------------- Flash attention (kv-split partials) ----------------------
// grid (32 q-tiles, 8 batches, 2 kv-splits) = 512 blocks; 256 thr = 4 waves
// x 32 q-rows. KVBLK=32; LDS 64KB (K 2x16K XOR-swizzled + V 2x16K chunk-major)
// -> 2 INDEPENDENT blocks/CU -> 2 waves/SIMD from different barrier groups.
__global__ __launch_bounds__(256, 2) void attn_kernel(
    const bf16_t* __restrict__ Q,   // (B, N, C)
    const bf16_t* __restrict__ Kt,  // (B, N, C)
    const bf16_t* __restrict__ V,   // (B, C, N)
    bf16_t* __restrict__ P0,        // (B, N, C) partial split 0
    bf16_t* __restrict__ P1,        // (B, N, C) partial split 1
    float* __restrict__ ML)         // [split][b*4096+q] x {m, l}
{
  __shared__ bf16_t k_lds[2][32 * 256];   // 16KB/buf; row=kv, 32 chunks of 16B
  __shared__ bf16_t v_lds[2][4 * 256 * 8];// 16KB/buf; chunk-major [g][c][8]

  const int b     = blockIdx.y;
  const int split = blockIdx.z;
  const long bo   = (long)b << 20;
  const bf16_t* q_t = Q  + bo;
  const bf16_t* k_t = Kt + bo + (long)split * 2048 * 256;
  const bf16_t* vb  = V  + bo + split * 2048;
  bf16_t*       po  = (split ? P1 : P0) + bo;

  const int tid = threadIdx.x;
  const int w   = tid >> 6, lane = tid & 63;
  const int ql  = lane & 31, hi = lane >> 5;
  const int q0  = blockIdx.x * 128 + w * 32;

  // staging source offsets (global elems). K: swizzle-inverse pre-applied.
  // V: chunk cl -> (c = cl&255, g = cl>>8), src = c*4096 + g*8 (+kv0).
  int kgoff[4], vgoff[4];
  #pragma unroll
  for (int it = 0; it < 4; ++it) {
    const int cl = it * 256 + tid;          // 1024 chunks of 16B each
    const int r  = cl >> 5, j = cl & 31;    // K: 32 rows x 32 chunks
    kgoff[it] = r * 256 + ((j ^ (r & 7)) << 3);
    const int c = cl & 255, g = cl >> 8;    // V: 4 kv-chunks x 256 rows
    vgoff[it] = c * 4096 + g * 8;
  }

  // Q fragments (B-operand): lane holds Q[q0+ql][cs*16 + hi*8 .. +8]
  bf16x8 qf[16];
  #pragma unroll
  for (int cs = 0; cs < 16; ++cs)
    qf[cs] = *(const bf16x8*)(q_t + (long)(q0 + ql) * 256 + cs * 16 + hi * 8);

  f32x16 o[8] = {};            // O^T[c = cb*32 + (reg&3)+8*(reg>>2)+4*hi][q=ql]
  float m2 = -1e30f, lsum = 0.f;
  const float SC2 = 0.0625f * 1.44269504f;   // scale * log2(e)

  // prologue: stage tile 0 into buf 0
  #pragma unroll
  for (int it = 0; it < 4; ++it)
    GLOAD_LDS(k_t + kgoff[it], &k_lds[0][(it * 256 + tid) * 8]);
  #pragma unroll
  for (int it = 0; it < 4; ++it)
    GLOAD_LDS(vb + vgoff[it], &v_lds[0][(it * 256 + tid) * 8]);

  int cur = 0;
  for (int t = 0; t < 64; ++t) {
    const int kv0 = t << 5;
    __syncthreads();                        // buf[cur] staged; prior reads done
    if (t < 63) {
      #pragma unroll
      for (int it = 0; it < 4; ++it)
        GLOAD_LDS(k_t + (long)(kv0 + 32) * 256 + kgoff[it],
                  &k_lds[cur ^ 1][(it * 256 + tid) * 8]);
      #pragma unroll
      for (int it = 0; it < 4; ++it)
        GLOAD_LDS(vb + (kv0 + 32) + vgoff[it],
                  &v_lds[cur ^ 1][(it * 256 + tid) * 8]);
    }

    // S^T = K . Q^T : one 32x32 tile, K from LDS (XOR-swizzled rows)
    f32x16 s0 = {};
    #pragma unroll
    for (int cs = 0; cs < 16; ++cs) {
      const int ch = cs * 2 + hi;
      bf16x8 kf = *(const bf16x8*)(
          &k_lds[cur][ql * 256 + ((ch ^ (ql & 7)) << 3)]);
      s0 = MFMA32(kf, qf[cs], s0);
    }

    // online softmax (log2 domain); lane owns q=ql, 16 kv rows lane-local
    float p0[16];
    #pragma unroll
    for (int i = 0; i < 16; ++i) p0[i] = s0[i] * SC2;
    float mx = p0[0];
    #pragma unroll
    for (int i = 1; i < 16; ++i) mx = fmaxf(mx, p0[i]);
    mx = fmaxf(mx, __shfl_xor(mx, 32));
    if (__any(mx > m2 + 11.5f)) {           // defer-max rescale
      const float mn = fmaxf(m2, mx);
      const float al = exp2f(m2 - mn);
      m2 = mn;
      lsum *= al;
      #pragma unroll
      for (int cb = 0; cb < 8; ++cb)
        #pragma unroll
        for (int i = 0; i < 16; ++i) o[cb][i] *= al;
    }
    float sm = 0.f;
    #pragma unroll
    for (int i = 0; i < 16; ++i) {
      p0[i] = exp2f(p0[i] - m2); sm += p0[i];
    }
    sm += __shfl_xor(sm, 32);
    lsum += sm;

    // P^T B-operand assembly: cvt_pk pairs + permlane32_swap (no LDS)
    bf16x8 pb[2];
    {
      unsigned wd[8];
      #pragma unroll
      for (int j = 0; j < 8; ++j) wd[j] = pk_bf16(p0[2 * j], p0[2 * j + 1]);
      lane32_swap(wd[0], wd[2]); lane32_swap(wd[1], wd[3]);
      lane32_swap(wd[4], wd[6]); lane32_swap(wd[5], wd[7]);
      union { unsigned u[4]; bf16x8 v; } a0, a1;
      a0.u[0] = wd[0]; a0.u[1] = wd[1]; a0.u[2] = wd[2]; a0.u[3] = wd[3];
      a1.u[0] = wd[4]; a1.u[1] = wd[5]; a1.u[2] = wd[6]; a1.u[3] = wd[7];
      pb[0] = a0.v; pb[1] = a1.v;
    }

    // O^T += V . P^T, V from LDS chunk-major [g][c]
    #pragma unroll
    for (int ks = 0; ks < 2; ++ks) {
      const int g = ks * 2 + hi;
      #pragma unroll
      for (int cb = 0; cb < 8; ++cb) {
        const int c = cb * 32 + ql;
        bf16x8 vf = *(const bf16x8*)(&v_lds[cur][(g * 256 + c) * 8]);
        o[cb] = MFMA32(vf, pb[ks], o[cb]);
      }
    }
    cur ^= 1;
  }

  // epilogue: store UNNORMALIZED O^T + (m, l)
  if (hi == 0) {
    float2 ml = make_float2(m2, lsum);
    *(float2*)(ML + ((long)split * 32768 + b * 4096 + q0 + ql) * 2) = ml;
  }
  bf16_t* hrow = po + (long)(q0 + ql) * 256;
  #pragma unroll
  for (int cb = 0; cb < 8; ++cb) {
    #pragma unroll
    for (int pg = 0; pg < 4; ++pg) {
      unsigned u0 = pk_bf16(o[cb][pg * 4 + 0], o[cb][pg * 4 + 1]);
      unsigned u1 = pk_bf16(o[cb][pg * 4 + 2], o[cb][pg * 4 + 3]);
      uint2 uu = make_uint2(u0, u1);
      *(uint2*)(hrow + cb * 32 + pg * 8 + hi * 4) = uu;
    }
  }
}

// ---------------- merge 2 kv-split partials -> h_t (B,N,C) bf16 -----------
__global__ __launch_bounds__(256) void attn_merge_kernel(
    const bf16_t* __restrict__ P0, const bf16_t* __restrict__ P1,
    const float* __restrict__ ML, bf16_t* __restrict__ Ht)
{
  const long e = ((long)blockIdx.x * 256 + threadIdx.x) * 8;   // 8 elems/thread
  const long r = e >> 8;                                       // flat q-row
  const float2 ml0 = *(const float2*)(ML + r * 2);
  const float2 ml1 = *(const float2*)(ML + (32768 + r) * 2);
  const float mm = fmaxf(ml0.x, ml1.x);
  const float w0 = exp2f(ml0.x - mm), w1 = exp2f(ml1.x - mm);
  const float il = 1.f / (ml0.y * w0 + ml1.y * w1);
  const float a0 = w0 * il, a1 = w1 * il;

  uint4 u0 = *(const uint4*)(P0 + e);
  uint4 u1 = *(const uint4*)(P1 + e);
  unsigned out[4];
  const unsigned* q0 = (const unsigned*)&u0;
  const unsigned* q1 = (const unsigned*)&u1;
  #pragma unroll
  for (int j = 0; j < 4; ++j) {
    float lo0 = __uint_as_float(q0[j] << 16);
    float hi0 = __uint_as_float(q0[j] & 0xffff0000u);
    float lo1 = __uint_as_float(q1[j] << 16);
    float hi1 = __uint_as_float(q1[j] & 0xffff0000u);
    out[j] = pk_bf16(fmaf(lo0, a0, lo1 * a1), fmaf(hi0, a0, hi1 * a1));
  }
  *(uint4*)(Ht + e) = *(uint4*)out;
}

extern "C" void kernel_launch(void* const* d_in, const int* in_sizes, int n_in,
                              void* d_out, int out_size, void* d_ws, size_t ws_size,
                              hipStream_t stream)
{
  const float* xy  = (const float*)d_in[0];
  const float* nw  = (const float*)d_in[1];
  const float* nb  = (const float*)d_in[2];
  const float* q_w = (const float*)d_in[3];
  const float* q_b = (const float*)d_in[4];
  const float* k_w = (const float*)d_in[5];
  const float* k_b = (const float*)d_in[6];
  const float* v_w = (const float*)d_in[7];
  const float* v_b = (const float*)d_in[8];
  const float* p_w = (const float*)d_in[9];
  const float* p_b = (const float*)d_in[10];
  float*  out = (float*)d_out;
  bf16_t* ws  = (bf16_t*)d_ws;

  const long SZ = (long)8 * 4096 * 256;
  bf16_t* wq   = ws;
  bf16_t* wk   = ws + 65536;
  bf16_t* wv   = ws + 131072;
  bf16_t* wp   = ws + 196608;
  bf16_t* hn_t = ws + 262144;
  bf16_t* yn_t = hn_t + SZ;
  bf16_t* q_t  = hn_t + 2 * SZ;
  bf16_t* k_t  = hn_t + 3 * SZ;
  bf16_t* vbuf = hn_t + 4 * SZ;
  float*  mlb  = (float*)(hn_t + 5 * SZ);   // 2 x 32768 x float2 = 512KB
  bf16_t* part0 = hn_t;                     // dead after v GEMM
  bf16_t* part1 = yn_t;                     // dead after q GEMM
  bf16_t* h_t   = q_t;                      // dead after attn

  const long nc = (long)4096 * 256;

  cvtw_kernel<<<dim3(64, 4), 256, 0, stream>>>(q_w, k_w, v_w, p_w, wq);

  gnorm_kernel<<<256, 256, 0, stream>>>(xy, nw, nb, hn_t, yn_t);

  gemm_st_kernel<false><<<dim3(64, 4, 8), 256, 0, stream>>>(
      yn_t, nc, wq, 0, q_t, nc, 256, q_b, 0, nullptr, 0);
  gemm_st_kernel<false><<<dim3(64, 4, 8), 256, 0, stream>>>(
      hn_t, nc, wk, 0, k_t, nc, 256, k_b, 0, nullptr, 0);
  gemm_st_kernel<false><<<dim3(4, 64, 8), 256, 0, stream>>>(
      wv, 0, hn_t, nc, vbuf, nc, 4096, v_b, 1, nullptr, 0);

  attn_kernel<<<dim3(32, 8, 2), 256, 0, stream>>>(q_t, k_t, vbuf,
                                                  part0, part1, mlb);

  attn_merge_kernel<<<4096, 256, 0, stream>>>(part0, part1, mlb, h_t);

  gemm_st_kernel<true><<<dim3(4, 64, 8), 256, 0, stream>>>(
      wp, 0, h_t, nc, out, nc, 4096, p_b, 1, xy, (long)512 * 4096);
}

// Round 12
// 305.689 us; speedup vs baseline: 1.6829x; 1.1937x over previous
//
#include <hip/hip_runtime.h>
#include <hip/hip_bf16.h>

using bf16_t  = __hip_bfloat16;
using bf16x8  = __attribute__((ext_vector_type(8))) __bf16;
using f32x4   = __attribute__((ext_vector_type(4))) float;
using f32x16  = __attribute__((ext_vector_type(16))) float;
using u32x2   = __attribute__((ext_vector_type(2))) unsigned;

#define MFMA32(a, b, c) __builtin_amdgcn_mfma_f32_32x32x16_bf16((a), (b), (c), 0, 0, 0)

#define GLOAD_LDS(g, l) __builtin_amdgcn_global_load_lds(                      \
    (const __attribute__((address_space(1))) void*)(g),                        \
    (__attribute__((address_space(3))) void*)(l), 16, 0, 0)

static __device__ __forceinline__ unsigned pk_bf16(float lo, float hi) {
  unsigned r;
  asm volatile("v_cvt_pk_bf16_f32 %0, %1, %2" : "=v"(r) : "v"(lo), "v"(hi));
  return r;
}

static __device__ __forceinline__ void lane32_swap(unsigned& a, unsigned& b) {
#if __has_builtin(__builtin_amdgcn_permlane32_swap)
  u32x2 r = __builtin_amdgcn_permlane32_swap(a, b, false, false);
  a = r[0]; b = r[1];
#else
  asm volatile("v_permlane32_swap_b32 %0, %1" : "+v"(a), "+v"(b));
#endif
}

// B=8, C=256, N=4096(=64x64), 16 groups of 16 channels. f32 I/O, bf16 internal.

// -------- prep: GroupNorm (256 blocks) + weight cvt (64 blocks) -----------
__global__ __launch_bounds__(256) void prep_kernel(
    const float* __restrict__ xy,
    const float* __restrict__ nw,
    const float* __restrict__ nb,
    const float* __restrict__ q_w, const float* __restrict__ k_w,
    const float* __restrict__ v_w, const float* __restrict__ p_w,
    bf16_t* __restrict__ hn_t,
    bf16_t* __restrict__ yn_t,
    bf16_t* __restrict__ wdst)
{
  const int bx  = blockIdx.x;
  const int tid = threadIdx.x;

  if (bx >= 256) {                 // ---- weight conversion path ----
    const int bx2 = bx - 256;      // 64 blocks x 256 thr x 4 elems = 65536/w
    const int i = (bx2 * 256 + tid) * 4;
    const float* srcs[4] = { q_w, k_w, v_w, p_w };
    #pragma unroll
    for (int wsel = 0; wsel < 4; ++wsel) {
      float4 v = *(const float4*)(srcs[wsel] + i);
      bf16_t* d = wdst + wsel * 65536 + i;
      d[0] = __float2bfloat16(v.x);
      d[1] = __float2bfloat16(v.y);
      d[2] = __float2bfloat16(v.z);
      d[3] = __float2bfloat16(v.w);
    }
    return;
  }

  const int b     = bx >> 5;
  const int rest  = bx & 31;
  const int which = rest >> 4;
  const int g     = rest & 15;

  const float* src = xy + (((long)b * 512 + which * 256 + g * 16) << 12);
  bf16_t* dst = (which ? yn_t : hn_t) + ((long)b << 20) + g * 16;

  float sum = 0.f, ss = 0.f;
  const float4* src4 = (const float4*)src;
  for (int i = tid; i < 16384; i += 256) {
    float4 v = src4[i];
    sum += (v.x + v.y) + (v.z + v.w);
    ss = fmaf(v.x, v.x, ss); ss = fmaf(v.y, v.y, ss);
    ss = fmaf(v.z, v.z, ss); ss = fmaf(v.w, v.w, ss);
  }
  #pragma unroll
  for (int off = 32; off > 0; off >>= 1) {
    sum += __shfl_down(sum, off);
    ss  += __shfl_down(ss, off);
  }
  __shared__ float rbuf[8];
  const int w = tid >> 6, lane = tid & 63;
  if (lane == 0) { rbuf[w] = sum; rbuf[4 + w] = ss; }
  __syncthreads();
  const float inv = 1.f / 65536.f;
  const float mu  = (rbuf[0] + rbuf[1] + rbuf[2] + rbuf[3]) * inv;
  const float var = (rbuf[4] + rbuf[5] + rbuf[6] + rbuf[7]) * inv - mu * mu;
  const float rs  = rsqrtf(var + 1e-6f);

  const int   cl = tid & 15;
  const float a  = nw[g * 16 + cl] * rs;
  const float c  = nb[g * 16 + cl] - mu * a;
  const float* srow = src + ((long)cl << 12);
  for (int n = tid >> 4; n < 4096; n += 16) {
    dst[((long)n << 8) + cl] = __float2bfloat16(fmaf(srow[n], a, c));
  }
}

// -------- unified staged QKV GEMM (single-phase contiguous staging) -------
// grid (64, 4, 24): z = which*8 + b. which 0: q_t = yn x wq^T; 1: k_t =
// hn x wk^T; 2: vbuf(C,N) = wv x hn^T (weights as A, coalesced store).
// Staging: LDS dest MUST be lane-contiguous (cl*8) for global_load_lds.
__global__ __launch_bounds__(256, 2) void gemm_qkv_kernel(
    const bf16_t* __restrict__ yn, const bf16_t* __restrict__ hn,
    const bf16_t* __restrict__ wqkv,
    bf16_t* __restrict__ q_t, bf16_t* __restrict__ k_t,
    bf16_t* __restrict__ vbuf,
    const float* __restrict__ qb, const float* __restrict__ kb,
    const float* __restrict__ vb)
{
  __shared__ bf16_t a_lds[64 * 256];
  __shared__ bf16_t b_lds[64 * 256];

  const int z     = blockIdx.z;
  const int which = z >> 3, b = z & 7;
  const long nc   = (long)4096 * 256;

  const bf16_t* Ag;
  const bf16_t* Bg;
  bf16_t* outp;
  const float* bias;
  long m0, n0;
  int Nn, brow;
  if (which == 0) {
    m0 = blockIdx.x * 64; n0 = blockIdx.y * 64;
    Ag = yn + b * nc + m0 * 256; Bg = wqkv + n0 * 256;
    outp = q_t + b * nc; bias = qb; Nn = 256; brow = 0;
  } else if (which == 1) {
    m0 = blockIdx.x * 64; n0 = blockIdx.y * 64;
    Ag = hn + b * nc + m0 * 256; Bg = wqkv + 65536 + n0 * 256;
    outp = k_t + b * nc; bias = kb; Nn = 256; brow = 0;
  } else {
    m0 = blockIdx.y * 64; n0 = blockIdx.x * 64;
    Ag = wqkv + 131072 + m0 * 256; Bg = hn + b * nc + n0 * 256;
    outp = vbuf + b * nc; bias = vb; Nn = 4096; brow = 1;
  }

  const int tid = threadIdx.x;
  const int w   = tid >> 6, lane = tid & 63;
  const int ql  = lane & 31, hi = lane >> 5;

  // stage both tiles (swizzle-inverse on global source; LDS dest linear)
  #pragma unroll
  for (int it = 0; it < 8; ++it) {
    const int cl  = it * 256 + tid;          // 2048 chunks of 16B
    const int r   = cl >> 5, j = cl & 31;    // 64 rows x 32 chunks
    const int off = r * 256 + ((j ^ (r & 7)) << 3);
    GLOAD_LDS(Ag + off, &a_lds[cl * 8]);
    GLOAD_LDS(Bg + off, &b_lds[cl * 8]);
  }
  __syncthreads();

  const int mb = (w & 1) * 32, nb = (w >> 1) * 32;
  const int sw = ql & 7;

  f32x16 acc = {};
  #pragma unroll
  for (int t = 0; t < 16; ++t) {
    const int ch = t * 2 + hi;
    bf16x8 af = *(const bf16x8*)(&a_lds[(mb + ql) * 256 + ((ch ^ sw) << 3)]);
    bf16x8 bf = *(const bf16x8*)(&b_lds[(nb + ql) * 256 + ((ch ^ sw) << 3)]);
    acc = MFMA32(af, bf, acc);
  }

  // D layout: col = ql, row = (r&3) + 8*(r>>2) + 4*hi
  #pragma unroll
  for (int r = 0; r < 16; ++r) {
    const int grow = (int)m0 + mb + (r & 3) + 8 * (r >> 2) + 4 * hi;
    const int gcol = (int)n0 + nb + ql;
    float vv = acc[r] + bias[brow ? grow : gcol];
    outp[(long)grow * Nn + gcol] = __float2bfloat16(vv);
  }
}

// -------- staged proj GEMM: out(C,N) f32 = wp x h^T + pb + resid ----------
__global__ __launch_bounds__(256, 2) void gemm_proj_kernel(
    const bf16_t* __restrict__ wp, const bf16_t* __restrict__ ht,
    float* __restrict__ outp, const float* __restrict__ pb,
    const float* __restrict__ xy)
{
  __shared__ bf16_t a_lds[64 * 256];
  __shared__ bf16_t b_lds[64 * 256];

  const int b   = blockIdx.z;
  const long nc = (long)4096 * 256;
  const long m0 = blockIdx.y * 64;            // channel tile (4)
  const long n0 = blockIdx.x * 64;            // spatial tile (64)
  const bf16_t* Ag = wp + m0 * 256;
  const bf16_t* Bg = ht + b * nc + n0 * 256;

  const int tid = threadIdx.x;
  const int w   = tid >> 6, lane = tid & 63;
  const int ql  = lane & 31, hi = lane >> 5;

  #pragma unroll
  for (int it = 0; it < 8; ++it) {
    const int cl  = it * 256 + tid;
    const int r   = cl >> 5, j = cl & 31;
    const int off = r * 256 + ((j ^ (r & 7)) << 3);
    GLOAD_LDS(Ag + off, &a_lds[cl * 8]);
    GLOAD_LDS(Bg + off, &b_lds[cl * 8]);
  }
  __syncthreads();

  const int mb = (w & 1) * 32, nb = (w >> 1) * 32;
  const int sw = ql & 7;

  f32x16 acc = {};
  #pragma unroll
  for (int t = 0; t < 16; ++t) {
    const int ch = t * 2 + hi;
    bf16x8 af = *(const bf16x8*)(&a_lds[(mb + ql) * 256 + ((ch ^ sw) << 3)]);
    bf16x8 bf = *(const bf16x8*)(&b_lds[(nb + ql) * 256 + ((ch ^ sw) << 3)]);
    acc = MFMA32(af, bf, acc);
  }

  const float* resid = xy + (long)b * 512 * 4096;
  #pragma unroll
  for (int r = 0; r < 16; ++r) {
    const int grow = (int)m0 + mb + (r & 3) + 8 * (r >> 2) + 4 * hi;
    const int gcol = (int)n0 + nb + ql;
    float vv = acc[r] + pb[grow] + resid[(long)grow * 4096 + gcol];
    outp[(long)b * nc + (long)grow * 4096 + gcol] = vv;
  }
}

// ---------------- Flash attention (kv-split partials) ----------------------
// grid (32 q-tiles, 8 batches, 2 kv-splits) = 512 blocks; 256 thr = 4 waves
// x 32 q-rows. KVBLK=32; LDS 64KB (K 2x16K XOR-swizzled + V 2x16K chunk-major)
// -> 2 INDEPENDENT blocks/CU -> 2 waves/SIMD from different barrier groups.
__global__ __launch_bounds__(256, 2) void attn_kernel(
    const bf16_t* __restrict__ Q,   // (B, N, C)
    const bf16_t* __restrict__ Kt,  // (B, N, C)
    const bf16_t* __restrict__ V,   // (B, C, N)
    bf16_t* __restrict__ P0,        // (B, N, C) partial split 0
    bf16_t* __restrict__ P1,        // (B, N, C) partial split 1
    float* __restrict__ ML)         // [split][b*4096+q] x {m, l}
{
  __shared__ bf16_t k_lds[2][32 * 256];   // 16KB/buf; row=kv, 32 chunks of 16B
  __shared__ bf16_t v_lds[2][4 * 256 * 8];// 16KB/buf; chunk-major [g][c][8]

  const int b     = blockIdx.y;
  const int split = blockIdx.z;
  const long bo   = (long)b << 20;
  const bf16_t* q_t = Q  + bo;
  const bf16_t* k_t = Kt + bo + (long)split * 2048 * 256;
  const bf16_t* vb  = V  + bo + split * 2048;
  bf16_t*       po  = (split ? P1 : P0) + bo;

  const int tid = threadIdx.x;
  const int w   = tid >> 6, lane = tid & 63;
  const int ql  = lane & 31, hi = lane >> 5;
  const int q0  = blockIdx.x * 128 + w * 32;

  // staging source offsets (global elems). K: swizzle-inverse pre-applied.
  // V: chunk cl -> (c = cl&255, g = cl>>8), src = c*4096 + g*8 (+kv0).
  int kgoff[4], vgoff[4];
  #pragma unroll
  for (int it = 0; it < 4; ++it) {
    const int cl = it * 256 + tid;          // 1024 chunks of 16B each
    const int r  = cl >> 5, j = cl & 31;    // K: 32 rows x 32 chunks
    kgoff[it] = r * 256 + ((j ^ (r & 7)) << 3);
    const int c = cl & 255, g = cl >> 8;    // V: 4 kv-chunks x 256 rows
    vgoff[it] = c * 4096 + g * 8;
  }

  // Q fragments (B-operand): lane holds Q[q0+ql][cs*16 + hi*8 .. +8]
  bf16x8 qf[16];
  #pragma unroll
  for (int cs = 0; cs < 16; ++cs)
    qf[cs] = *(const bf16x8*)(q_t + (long)(q0 + ql) * 256 + cs * 16 + hi * 8);

  f32x16 o[8] = {};            // O^T[c = cb*32 + (reg&3)+8*(reg>>2)+4*hi][q=ql]
  float m2 = -1e30f, lsum = 0.f;
  const float SC2 = 0.0625f * 1.44269504f;   // scale * log2(e)

  // prologue: stage tile 0 into buf 0
  #pragma unroll
  for (int it = 0; it < 4; ++it)
    GLOAD_LDS(k_t + kgoff[it], &k_lds[0][(it * 256 + tid) * 8]);
  #pragma unroll
  for (int it = 0; it < 4; ++it)
    GLOAD_LDS(vb + vgoff[it], &v_lds[0][(it * 256 + tid) * 8]);

  int cur = 0;
  for (int t = 0; t < 64; ++t) {
    const int kv0 = t << 5;
    __syncthreads();                        // buf[cur] staged; prior reads done
    if (t < 63) {
      #pragma unroll
      for (int it = 0; it < 4; ++it)
        GLOAD_LDS(k_t + (long)(kv0 + 32) * 256 + kgoff[it],
                  &k_lds[cur ^ 1][(it * 256 + tid) * 8]);
      #pragma unroll
      for (int it = 0; it < 4; ++it)
        GLOAD_LDS(vb + (kv0 + 32) + vgoff[it],
                  &v_lds[cur ^ 1][(it * 256 + tid) * 8]);
    }

    // S^T = K . Q^T : one 32x32 tile, K from LDS (XOR-swizzled rows)
    f32x16 s0 = {};
    #pragma unroll
    for (int cs = 0; cs < 16; ++cs) {
      const int ch = cs * 2 + hi;
      bf16x8 kf = *(const bf16x8*)(
          &k_lds[cur][ql * 256 + ((ch ^ (ql & 7)) << 3)]);
      s0 = MFMA32(kf, qf[cs], s0);
    }

    // online softmax (log2 domain); lane owns q=ql, 16 kv rows lane-local
    float p0[16];
    #pragma unroll
    for (int i = 0; i < 16; ++i) p0[i] = s0[i] * SC2;
    float mx = p0[0];
    #pragma unroll
    for (int i = 1; i < 16; ++i) mx = fmaxf(mx, p0[i]);
    mx = fmaxf(mx, __shfl_xor(mx, 32));
    if (__any(mx > m2 + 11.5f)) {           // defer-max rescale
      const float mn = fmaxf(m2, mx);
      const float al = exp2f(m2 - mn);
      m2 = mn;
      lsum *= al;
      #pragma unroll
      for (int cb = 0; cb < 8; ++cb)
        #pragma unroll
        for (int i = 0; i < 16; ++i) o[cb][i] *= al;
    }
    float sm = 0.f;
    #pragma unroll
    for (int i = 0; i < 16; ++i) {
      p0[i] = exp2f(p0[i] - m2); sm += p0[i];
    }
    sm += __shfl_xor(sm, 32);
    lsum += sm;

    // P^T B-operand assembly: cvt_pk pairs + permlane32_swap (no LDS)
    bf16x8 pb[2];
    {
      unsigned wd[8];
      #pragma unroll
      for (int j = 0; j < 8; ++j) wd[j] = pk_bf16(p0[2 * j], p0[2 * j + 1]);
      lane32_swap(wd[0], wd[2]); lane32_swap(wd[1], wd[3]);
      lane32_swap(wd[4], wd[6]); lane32_swap(wd[5], wd[7]);
      union { unsigned u[4]; bf16x8 v; } a0, a1;
      a0.u[0] = wd[0]; a0.u[1] = wd[1]; a0.u[2] = wd[2]; a0.u[3] = wd[3];
      a1.u[0] = wd[4]; a1.u[1] = wd[5]; a1.u[2] = wd[6]; a1.u[3] = wd[7];
      pb[0] = a0.v; pb[1] = a1.v;
    }

    // O^T += V . P^T, V from LDS chunk-major [g][c]
    #pragma unroll
    for (int ks = 0; ks < 2; ++ks) {
      const int g = ks * 2 + hi;
      #pragma unroll
      for (int cb = 0; cb < 8; ++cb) {
        const int c = cb * 32 + ql;
        bf16x8 vf = *(const bf16x8*)(&v_lds[cur][(g * 256 + c) * 8]);
        o[cb] = MFMA32(vf, pb[ks], o[cb]);
      }
    }
    cur ^= 1;
  }

  // epilogue: store UNNORMALIZED O^T + (m, l)
  if (hi == 0) {
    float2 ml = make_float2(m2, lsum);
    *(float2*)(ML + ((long)split * 32768 + b * 4096 + q0 + ql) * 2) = ml;
  }
  bf16_t* hrow = po + (long)(q0 + ql) * 256;
  #pragma unroll
  for (int cb = 0; cb < 8; ++cb) {
    #pragma unroll
    for (int pg = 0; pg < 4; ++pg) {
      unsigned u0 = pk_bf16(o[cb][pg * 4 + 0], o[cb][pg * 4 + 1]);
      unsigned u1 = pk_bf16(o[cb][pg * 4 + 2], o[cb][pg * 4 + 3]);
      uint2 uu = make_uint2(u0, u1);
      *(uint2*)(hrow + cb * 32 + pg * 8 + hi * 4) = uu;
    }
  }
}

// ---------------- merge 2 kv-split partials -> h_t (B,N,C) bf16 -----------
__global__ __launch_bounds__(256) void attn_merge_kernel(
    const bf16_t* __restrict__ P0, const bf16_t* __restrict__ P1,
    const float* __restrict__ ML, bf16_t* __restrict__ Ht)
{
  const long e = ((long)blockIdx.x * 256 + threadIdx.x) * 8;   // 8 elems/thread
  const long r = e >> 8;                                       // flat q-row
  const float2 ml0 = *(const float2*)(ML + r * 2);
  const float2 ml1 = *(const float2*)(ML + (32768 + r) * 2);
  const float mm = fmaxf(ml0.x, ml1.x);
  const float w0 = exp2f(ml0.x - mm), w1 = exp2f(ml1.x - mm);
  const float il = 1.f / (ml0.y * w0 + ml1.y * w1);
  const float a0 = w0 * il, a1 = w1 * il;

  uint4 u0 = *(const uint4*)(P0 + e);
  uint4 u1 = *(const uint4*)(P1 + e);
  unsigned out[4];
  const unsigned* q0 = (const unsigned*)&u0;
  const unsigned* q1 = (const unsigned*)&u1;
  #pragma unroll
  for (int j = 0; j < 4; ++j) {
    float lo0 = __uint_as_float(q0[j] << 16);
    float hi0 = __uint_as_float(q0[j] & 0xffff0000u);
    float lo1 = __uint_as_float(q1[j] << 16);
    float hi1 = __uint_as_float(q1[j] & 0xffff0000u);
    out[j] = pk_bf16(fmaf(lo0, a0, lo1 * a1), fmaf(hi0, a0, hi1 * a1));
  }
  *(uint4*)(Ht + e) = *(uint4*)out;
}

extern "C" void kernel_launch(void* const* d_in, const int* in_sizes, int n_in,
                              void* d_out, int out_size, void* d_ws, size_t ws_size,
                              hipStream_t stream)
{
  const float* xy  = (const float*)d_in[0];
  const float* nw  = (const float*)d_in[1];
  const float* nb  = (const float*)d_in[2];
  const float* q_w = (const float*)d_in[3];
  const float* q_b = (const float*)d_in[4];
  const float* k_w = (const float*)d_in[5];
  const float* k_b = (const float*)d_in[6];
  const float* v_w = (const float*)d_in[7];
  const float* v_b = (const float*)d_in[8];
  const float* p_w = (const float*)d_in[9];
  const float* p_b = (const float*)d_in[10];
  float*  out = (float*)d_out;
  bf16_t* ws  = (bf16_t*)d_ws;

  const long SZ = (long)8 * 4096 * 256;
  bf16_t* wqkv = ws;                        // wq,wk,wv,wp contiguous
  bf16_t* wp   = ws + 196608;
  bf16_t* hn_t = ws + 262144;
  bf16_t* yn_t = hn_t + SZ;
  bf16_t* q_t  = hn_t + 2 * SZ;
  bf16_t* k_t  = hn_t + 3 * SZ;
  bf16_t* vbuf = hn_t + 4 * SZ;
  float*  mlb  = (float*)(hn_t + 5 * SZ);   // 2 x 32768 x float2 = 512KB
  bf16_t* part0 = hn_t;                     // dead after v GEMM
  bf16_t* part1 = yn_t;                     // dead after q GEMM
  bf16_t* h_t   = q_t;                      // dead after attn

  prep_kernel<<<320, 256, 0, stream>>>(xy, nw, nb, q_w, k_w, v_w, p_w,
                                       hn_t, yn_t, wqkv);

  gemm_qkv_kernel<<<dim3(64, 4, 24), 256, 0, stream>>>(
      yn_t, hn_t, wqkv, q_t, k_t, vbuf, q_b, k_b, v_b);

  attn_kernel<<<dim3(32, 8, 2), 256, 0, stream>>>(q_t, k_t, vbuf,
                                                  part0, part1, mlb);

  attn_merge_kernel<<<4096, 256, 0, stream>>>(part0, part1, mlb, h_t);

  gemm_proj_kernel<<<dim3(64, 4, 8), 256, 0, stream>>>(wp, h_t, out, p_b, xy);
}